// Round 9
// baseline (143.064 us; speedup 1.0000x reference)
//
#include <hip/hip_runtime.h>

#define TPB 256

// r23: hull-walk elimination. r8: main ~40us, Jarvis = ~2800 serially-chained
// ops (~60% of kernel), worst-lane gated. Replace start-min + Jarvis with an
// order-free hull-area formula:
//   ch = 0.5*( sum_i ca_i*[all B left of A-edge i]     <- aa's from clip p2
//            + sum_j cb_j*[all A left of B-edge j]     <- aa's from clip p1
//            + sum_ij cross(A_i,B_j)*(bridgeAB - bridgeBA) )
// bridgeAB(i,j): 4 neighbor crosses (convexity => neighbor test sufficient;
// a convex curve meets a line <=2 times). Handles 4-bridge X-crossings and
// containment (-> max(area_a,area_b)) automatically. Branchless 64-pair
// sweep, ~22 VALU/pair, zero serial chains. Reassociation tolerance already
// proven by r21 (absmax stayed 0.0). Clip/epilogue/finalize: r22.
__global__ __launch_bounds__(TPB, 2) void ciou_main(
    const float* __restrict__ A,
    const float* __restrict__ Bq,
    double* __restrict__ partial,
    int nbatch, int tail)
{
    const int t = threadIdx.x;
    const int i0 = blockIdx.x * TPB + t;
    const bool live = !tail || (i0 < nbatch);
    const int i = live ? i0 : (nbatch - 1);

    float ax0,ax1,ax2,ax3,ax4,ax5,ax6,ax7;
    float ay0,ay1,ay2,ay3,ay4,ay5,ay6,ay7;
    float bx0,bx1,bx2,bx3,bx4,bx5,bx6,bx7;
    float by0,by1,by2,by3,by4,by5,by6,by7;
    {
        const float4* pa = (const float4*)(A + (size_t)i * 16);
        const float4* pb = (const float4*)(Bq + (size_t)i * 16);
        float4 q;
        q = pa[0]; ax0=q.x; ay0=q.y; ax1=q.z; ay1=q.w;
        q = pa[1]; ax2=q.x; ay2=q.y; ax3=q.z; ay3=q.w;
        q = pa[2]; ax4=q.x; ay4=q.y; ax5=q.z; ay5=q.w;
        q = pa[3]; ax6=q.x; ay6=q.y; ax7=q.z; ay7=q.w;
        q = pb[0]; bx0=q.x; by0=q.y; bx1=q.z; by1=q.w;
        q = pb[1]; bx2=q.x; by2=q.y; bx3=q.z; by3=q.w;
        q = pb[2]; bx4=q.x; by4=q.y; bx5=q.z; by5=q.w;
        q = pb[3]; bx6=q.x; by6=q.y; bx7=q.z; by7=q.w;
    }

    // Edge vectors and shoelace crosses (hoisted once, reused everywhere).
#define MKEA(I,IN) float eax##I = ax##IN - ax##I, eay##I = ay##IN - ay##I;
#define MKEB(I,IN) float ebx##I = bx##IN - bx##I, eby##I = by##IN - by##I;
    MKEA(0,1) MKEA(1,2) MKEA(2,3) MKEA(3,4)
    MKEA(4,5) MKEA(5,6) MKEA(6,7) MKEA(7,0)
    MKEB(0,1) MKEB(1,2) MKEB(2,3) MKEB(3,4)
    MKEB(4,5) MKEB(5,6) MKEB(6,7) MKEB(7,0)
#define MKCA(I,IN) float ca##I = ax##I*ay##IN - ay##I*ax##IN;
#define MKCB(I,IN) float cb##I = bx##I*by##IN - by##I*bx##IN;
    MKCA(0,1) MKCA(1,2) MKCA(2,3) MKCA(3,4)
    MKCA(4,5) MKCA(5,6) MKCA(6,7) MKCA(7,0)
    MKCB(0,1) MKCB(1,2) MKCB(2,3) MKCB(3,4)
    MKCB(4,5) MKCB(5,6) MKCB(6,7) MKCB(7,0)
    float area_a = 0.5f * (((ca0+ca1)+(ca2+ca3)) + ((ca4+ca5)+(ca6+ca7)));
    float area_b = 0.5f * (((cb0+cb1)+(cb2+cb3)) + ((cb4+cb5)+(cb6+cb7)));

    // ---- Intersection clip + hull-edge masks ----
    // HP: halfplane test along P-edge (aa + t*bb >= 0) AND accumulate the
    // "all P-polygon vertices left of this Q-edge" mask (MK *= aa>=0):
    // pass 1 (P=A-edges, Q=B) fills mb_j; pass 2 fills ma_i.
    float inter2 = 0.f;
    float mb0=1.f,mb1=1.f,mb2=1.f,mb3=1.f,mb4=1.f,mb5=1.f,mb6=1.f,mb7=1.f;
    float ma0=1.f,ma1=1.f,ma2=1.f,ma3=1.f,ma4=1.f,ma5=1.f,ma6=1.f,ma7=1.f;

#define HP(T0,T1,EX,EY,CC,MK) { \
        float aa = EX*Py - EY*Px + (CC); \
        float bb = EX*Dy - EY*Dx; \
        MK = (aa >= 0.f) ? MK : 0.f; \
        float tc = __fdividef(-aa, bb); \
        float h = bb * 1e38f; \
        T0 = fmaxf(T0, fminf(tc, h)); \
        T1 = fminf(T1, fmaxf(tc, h)); }

#define HPB HP(t0a,t1a, ebx0,eby0,cb0,mb0) HP(t0b,t1b, ebx1,eby1,cb1,mb1) \
            HP(t0a,t1a, ebx2,eby2,cb2,mb2) HP(t0b,t1b, ebx3,eby3,cb3,mb3) \
            HP(t0a,t1a, ebx4,eby4,cb4,mb4) HP(t0b,t1b, ebx5,eby5,cb5,mb5) \
            HP(t0a,t1a, ebx6,eby6,cb6,mb6) HP(t0b,t1b, ebx7,eby7,cb7,mb7)
#define HPA HP(t0a,t1a, eax0,eay0,ca0,ma0) HP(t0b,t1b, eax1,eay1,ca1,ma1) \
            HP(t0a,t1a, eax2,eay2,ca2,ma2) HP(t0b,t1b, eax3,eay3,ca3,ma3) \
            HP(t0a,t1a, eax4,eay4,ca4,ma4) HP(t0b,t1b, eax5,eay5,ca5,ma5) \
            HP(t0a,t1a, eax6,eay6,ca6,ma6) HP(t0b,t1b, eax7,eay7,ca7,ma7)

#define EDGE(PX,PY,DX,DY,CPD,HPS) { \
        const float Px = (PX), Py = (PY); \
        const float Dx = (DX), Dy = (DY); \
        float t0a = 0.f, t1a = 1.f, t0b = 0.f, t1b = 1.f; \
        HPS \
        float dt = fminf(t1a, t1b) - fmaxf(t0a, t0b); \
        inter2 += fmaxf(dt, 0.f) * (CPD); }

    EDGE(ax0,ay0, eax0,eay0, ca0, HPB) EDGE(ax1,ay1, eax1,eay1, ca1, HPB)
    EDGE(ax2,ay2, eax2,eay2, ca2, HPB) EDGE(ax3,ay3, eax3,eay3, ca3, HPB)
    EDGE(ax4,ay4, eax4,eay4, ca4, HPB) EDGE(ax5,ay5, eax5,eay5, ca5, HPB)
    EDGE(ax6,ay6, eax6,eay6, ca6, HPB) EDGE(ax7,ay7, eax7,eay7, ca7, HPB)
    EDGE(bx0,by0, ebx0,eby0, cb0, HPA) EDGE(bx1,by1, ebx1,eby1, cb1, HPA)
    EDGE(bx2,by2, ebx2,eby2, cb2, HPA) EDGE(bx3,by3, ebx3,eby3, cb3, HPA)
    EDGE(bx4,by4, ebx4,eby4, cb4, HPA) EDGE(bx5,by5, ebx5,eby5, cb5, HPA)
    EDGE(bx6,by6, ebx6,eby6, cb6, HPA) EDGE(bx7,by7, ebx7,eby7, cb7, HPA)

    float inter = fmaxf(0.5f * inter2, 0.f);
    float uni = area_a + area_b - inter;
    float iou = __fdividef(inter, uni);

    // ---- Hull area: masked polygon edges + bridge-pair sweep ----
    // Polygon-edge part (masks consume ca/cb; computed as a small tree).
    float eS = ((ca0*ma0 + ca1*ma1) + (ca2*ma2 + ca3*ma3))
             + ((ca4*ma4 + ca5*ma5) + (ca6*ma6 + ca7*ma7))
             + ((cb0*mb0 + cb1*mb1) + (cb2*mb2 + cb3*mb3))
             + ((cb4*mb4 + cb5*mb5) + (cb6*mb6 + cb7*mb7));

    // Bridge sweep: ordered pair A_i->B_j is a hull edge iff A_{i+1} left
    // (c1>=0), A_{i-1} left (c2<=0, via ea_{i-1}), B_{j+1} left (c3>=0),
    // B_{j-1} left (c4<=0). Reverse bridge B_j->A_i: all signs flipped.
    float hb0 = 0.f, hb1 = 0.f, hb2 = 0.f, hb3 = 0.f;
#define BR(AXI,AYI,EAXI,EAYI,EAXP,EAYP, BXJ,BYJ,EBXJ,EBYJ,EBXP,EBYP, ACC) { \
        float Dx = (BXJ)-(AXI), Dy = (BYJ)-(AYI); \
        float c1 = Dx*(EAYI) - Dy*(EAXI); \
        float c2 = Dx*(EAYP) - Dy*(EAXP); \
        float c3 = Dx*(EBYJ) - Dy*(EBXJ); \
        float c4 = Dx*(EBYP) - Dy*(EBXP); \
        float cx = (AXI)*(BYJ) - (AYI)*(BXJ); \
        bool ab = (c1 >= 0.f) & (c2 <= 0.f) & (c3 >= 0.f) & (c4 <= 0.f); \
        bool ba = (c1 <= 0.f) & (c2 >= 0.f) & (c3 <= 0.f) & (c4 >= 0.f); \
        float sgn = (ab ? 1.f : 0.f) - (ba ? 1.f : 0.f); \
        ACC = fmaf(sgn, cx, ACC); }

#define BRROW(AXI,AYI,EAXI,EAYI,EAXP,EAYP) \
    BR(AXI,AYI,EAXI,EAYI,EAXP,EAYP, bx0,by0, ebx0,eby0, ebx7,eby7, hb0) \
    BR(AXI,AYI,EAXI,EAYI,EAXP,EAYP, bx1,by1, ebx1,eby1, ebx0,eby0, hb1) \
    BR(AXI,AYI,EAXI,EAYI,EAXP,EAYP, bx2,by2, ebx2,eby2, ebx1,eby1, hb2) \
    BR(AXI,AYI,EAXI,EAYI,EAXP,EAYP, bx3,by3, ebx3,eby3, ebx2,eby2, hb3) \
    BR(AXI,AYI,EAXI,EAYI,EAXP,EAYP, bx4,by4, ebx4,eby4, ebx3,eby3, hb0) \
    BR(AXI,AYI,EAXI,EAYI,EAXP,EAYP, bx5,by5, ebx5,eby5, ebx4,eby4, hb1) \
    BR(AXI,AYI,EAXI,EAYI,EAXP,EAYP, bx6,by6, ebx6,eby6, ebx5,eby5, hb2) \
    BR(AXI,AYI,EAXI,EAYI,EAXP,EAYP, bx7,by7, ebx7,eby7, ebx6,eby6, hb3)

    BRROW(ax0,ay0, eax0,eay0, eax7,eay7)
    BRROW(ax1,ay1, eax1,eay1, eax0,eay0)
    BRROW(ax2,ay2, eax2,eay2, eax1,eay1)
    BRROW(ax3,ay3, eax3,eay3, eax2,eay2)
    BRROW(ax4,ay4, eax4,eay4, eax3,eay3)
    BRROW(ax5,ay5, eax5,eay5, eax4,eay4)
    BRROW(ax6,ay6, eax6,eay6, eax5,eay5)
    BRROW(ax7,ay7, eax7,eay7, eax6,eay6)

    float ch = 0.5f * (eS + ((hb0 + hb1) + (hb2 + hb3)));

    float val = iou - __fdividef(ch - uni, ch);
    float v = live ? val : 0.f;

    // ---- epilogue: shuffle -> LDS(16B) -> ONE plain store. Zero waits. ----
    #pragma unroll
    for (int off = 32; off > 0; off >>= 1) v += __shfl_down(v, off);
    __shared__ float wsum[4];
    int lane = t & 63, wid = t >> 6;
    if (lane == 0) wsum[wid] = v;
    __syncthreads();
    if (t == 0) {
        partial[blockIdx.x] = (double)wsum[0] + (double)wsum[1]
                            + (double)wsum[2] + (double)wsum[3];
    }
}

__global__ __launch_bounds__(256) void ciou_finalize(
    const double* __restrict__ partial, float* __restrict__ out,
    int nparts, int nbatch)
{
    double v = 0.0;
    for (int j = threadIdx.x; j < nparts; j += 256) v += partial[j];
    #pragma unroll
    for (int off = 32; off > 0; off >>= 1) v += __shfl_down(v, off);
    __shared__ double s[4];
    int lane = threadIdx.x & 63, wid = threadIdx.x >> 6;
    if (lane == 0) s[wid] = v;
    __syncthreads();
    if (threadIdx.x == 0)
        out[0] = (float)((s[0] + s[1] + s[2] + s[3]) / (double)nbatch);
}

extern "C" void kernel_launch(void* const* d_in, const int* in_sizes, int n_in,
                              void* d_out, int out_size, void* d_ws, size_t ws_size,
                              hipStream_t stream) {
    const float* a = (const float*)d_in[0];
    const float* b = (const float*)d_in[1];
    float* out = (float*)d_out;
    int nbatch = in_sizes[0] / 16;
    int nblocks = (nbatch + TPB - 1) / TPB;   // 262144 -> 1024, exact
    int tail = (nblocks * TPB != nbatch) ? 1 : 0;
    double* partial = (double*)d_ws;   // fully overwritten each call; no memset
    ciou_main<<<nblocks, TPB, 0, stream>>>(a, b, partial, nbatch, tail);
    ciou_finalize<<<1, 256, 0, stream>>>(partial, out, nblocks, nbatch);
}

// Round 10
// 102.077 us; speedup vs baseline: 1.4015x; 1.4015x over previous
//
#include <hip/hip_runtime.h>

#define TPB 256

// r24: hull-formula retry, pressure-engineered. r23 proved the bridge/mask
// math EXACT (absmax 0.0) but spilled (VGPR 128, 83MB scratch): in-clip
// masks + hoistable 64-cross sweep blew the live set. Fixes:
//   1. clip = r22 VERBATIM (proven no-spill); masks now free byproducts of
//      the sweep: c3(i,j)=cross(D,eb_j)==aa(i,j), so mbmin_j=min_i c3 and
//      row-local rmax_i=max_j c1 (aa_BA=-c1) -> only 8 persistent mask regs.
//   2. row-chained asm pins: row i's coords laundered with hbp/hbm as
//      inputs -> scheduler cannot hoist later rows' crosses (r21/r23 bug).
//   3. sgn via mn=min(c1,-c2,c3,-c4)>=0 / mx=max(..)<=0 (v_min3/v_max3,
//      free modifiers).
// Live ~110 < 128. Jarvis + start-min deleted (~2850 ops -> ~1550).
__global__ __launch_bounds__(TPB, 2) void ciou_main(
    const float* __restrict__ A,
    const float* __restrict__ Bq,
    double* __restrict__ partial,
    int nbatch, int tail)
{
    const int t = threadIdx.x;
    const int i0 = blockIdx.x * TPB + t;
    const bool live = !tail || (i0 < nbatch);
    const int i = live ? i0 : (nbatch - 1);

    float ax0,ax1,ax2,ax3,ax4,ax5,ax6,ax7;
    float ay0,ay1,ay2,ay3,ay4,ay5,ay6,ay7;
    float bx0,bx1,bx2,bx3,bx4,bx5,bx6,bx7;
    float by0,by1,by2,by3,by4,by5,by6,by7;
    {
        const float4* pa = (const float4*)(A + (size_t)i * 16);
        const float4* pb = (const float4*)(Bq + (size_t)i * 16);
        float4 q;
        q = pa[0]; ax0=q.x; ay0=q.y; ax1=q.z; ay1=q.w;
        q = pa[1]; ax2=q.x; ay2=q.y; ax3=q.z; ay3=q.w;
        q = pa[2]; ax4=q.x; ay4=q.y; ax5=q.z; ay5=q.w;
        q = pa[3]; ax6=q.x; ay6=q.y; ax7=q.z; ay7=q.w;
        q = pb[0]; bx0=q.x; by0=q.y; bx1=q.z; by1=q.w;
        q = pb[1]; bx2=q.x; by2=q.y; bx3=q.z; by3=q.w;
        q = pb[2]; bx4=q.x; by4=q.y; bx5=q.z; by5=q.w;
        q = pb[3]; bx6=q.x; by6=q.y; bx7=q.z; by7=q.w;
    }

    // Edge vectors and shoelace crosses (hoisted once, reused everywhere).
#define MKEA(I,IN) float eax##I = ax##IN - ax##I, eay##I = ay##IN - ay##I;
#define MKEB(I,IN) float ebx##I = bx##IN - bx##I, eby##I = by##IN - by##I;
    MKEA(0,1) MKEA(1,2) MKEA(2,3) MKEA(3,4)
    MKEA(4,5) MKEA(5,6) MKEA(6,7) MKEA(7,0)
    MKEB(0,1) MKEB(1,2) MKEB(2,3) MKEB(3,4)
    MKEB(4,5) MKEB(5,6) MKEB(6,7) MKEB(7,0)
#define MKCA(I,IN) float ca##I = ax##I*ay##IN - ay##I*ax##IN;
#define MKCB(I,IN) float cb##I = bx##I*by##IN - by##I*bx##IN;
    MKCA(0,1) MKCA(1,2) MKCA(2,3) MKCA(3,4)
    MKCA(4,5) MKCA(5,6) MKCA(6,7) MKCA(7,0)
    MKCB(0,1) MKCB(1,2) MKCB(2,3) MKCB(3,4)
    MKCB(4,5) MKCB(5,6) MKCB(6,7) MKCB(7,0)
    float area_a = 0.5f * (((ca0+ca1)+(ca2+ca3)) + ((ca4+ca5)+(ca6+ca7)));
    float area_b = 0.5f * (((cb0+cb1)+(cb2+cb3)) + ((cb4+cb5)+(cb6+cb7)));

    // ---- Intersection: Green's theorem over clipped edges (r22 verbatim) --
    float inter2 = 0.f;

#define HP(T0,T1,EX,EY,CC) { \
        float aa = EX*Py - EY*Px + (CC); \
        float bb = EX*Dy - EY*Dx; \
        float tc = __fdividef(-aa, bb); \
        float h = bb * 1e38f; \
        T0 = fmaxf(T0, fminf(tc, h)); \
        T1 = fminf(T1, fmaxf(tc, h)); }

#define HPB HP(t0a,t1a, ebx0,eby0,cb0) HP(t0b,t1b, ebx1,eby1,cb1) \
            HP(t0a,t1a, ebx2,eby2,cb2) HP(t0b,t1b, ebx3,eby3,cb3) \
            HP(t0a,t1a, ebx4,eby4,cb4) HP(t0b,t1b, ebx5,eby5,cb5) \
            HP(t0a,t1a, ebx6,eby6,cb6) HP(t0b,t1b, ebx7,eby7,cb7)
#define HPA HP(t0a,t1a, eax0,eay0,ca0) HP(t0b,t1b, eax1,eay1,ca1) \
            HP(t0a,t1a, eax2,eay2,ca2) HP(t0b,t1b, eax3,eay3,ca3) \
            HP(t0a,t1a, eax4,eay4,ca4) HP(t0b,t1b, eax5,eay5,ca5) \
            HP(t0a,t1a, eax6,eay6,ca6) HP(t0b,t1b, eax7,eay7,ca7)

#define EDGE(PX,PY,DX,DY,CPD,HPS) { \
        const float Px = (PX), Py = (PY); \
        const float Dx = (DX), Dy = (DY); \
        float t0a = 0.f, t1a = 1.f, t0b = 0.f, t1b = 1.f; \
        HPS \
        float dt = fminf(t1a, t1b) - fmaxf(t0a, t0b); \
        inter2 += fmaxf(dt, 0.f) * (CPD); }

    EDGE(ax0,ay0, eax0,eay0, ca0, HPB) EDGE(ax1,ay1, eax1,eay1, ca1, HPB)
    EDGE(ax2,ay2, eax2,eay2, ca2, HPB) EDGE(ax3,ay3, eax3,eay3, ca3, HPB)
    EDGE(ax4,ay4, eax4,eay4, ca4, HPB) EDGE(ax5,ay5, eax5,eay5, ca5, HPB)
    EDGE(ax6,ay6, eax6,eay6, ca6, HPB) EDGE(ax7,ay7, eax7,eay7, ca7, HPB)
    EDGE(bx0,by0, ebx0,eby0, cb0, HPA) EDGE(bx1,by1, ebx1,eby1, cb1, HPA)
    EDGE(bx2,by2, ebx2,eby2, cb2, HPA) EDGE(bx3,by3, ebx3,eby3, cb3, HPA)
    EDGE(bx4,by4, ebx4,eby4, cb4, HPA) EDGE(bx5,by5, ebx5,eby5, cb5, HPA)
    EDGE(bx6,by6, ebx6,eby6, cb6, HPA) EDGE(bx7,by7, ebx7,eby7, cb7, HPA)

    float inter = fmaxf(0.5f * inter2, 0.f);
    float uni = area_a + area_b - inter;
    float iou = __fdividef(inter, uni);

    // ---- Hull area: bridge-pair sweep with byproduct masks (r24) ----
    // Ordered bridge A_i->B_j on hull iff c1>=0 & c2<=0 & c3>=0 & c4<=0
    // (neighbor test suffices by convexity; validated exact in r23).
    // c3(i,j) = cross(D, eb_j) == aa(i,j)  -> mbmin_j = min_i c3.
    // aa_BA(j,i) = -c1                     -> row mask: rmax_i = max_j c1.
    float hbp = 0.f, hbm = 0.f, eSa = 0.f;
    float mbmin0=1e38f, mbmin1=1e38f, mbmin2=1e38f, mbmin3=1e38f,
          mbmin4=1e38f, mbmin5=1e38f, mbmin6=1e38f, mbmin7=1e38f;

#define BR2(EBXJ,EBYJ, EBXP,EBYP, BXJ,BYJ, MB) { \
        float Dx = (BXJ) - rax, Dy = (BYJ) - ray; \
        float c1 = Dx*reay - Dy*reax; \
        float c2 = Dx*peay - Dy*peax; \
        float c3 = Dx*(EBYJ) - Dy*(EBXJ); \
        float c4 = Dx*(EBYP) - Dy*(EBXP); \
        float cx = rax*(BYJ) - ray*(BXJ); \
        MB = fminf(MB, c3); \
        rmax = fmaxf(rmax, c1); \
        float mn = fminf(fminf(c1, -c2), fminf(c3, -c4)); \
        float mx = fmaxf(fmaxf(c1, -c2), fmaxf(c3, -c4)); \
        hbp += (mn >= 0.f) ? cx : 0.f; \
        hbm += (mx <= 0.f) ? cx : 0.f; }

    // Row: A_i coords laundered with hbp/hbm as inputs -> rows cannot be
    // reordered/hoisted en masse by the scheduler (r21/r23 spill mechanism).
#define BRROW(AXI,AYI, EAXI,EAYI, EAXP,EAYP, CAI) { \
        float rax = (AXI), ray = (AYI); \
        asm volatile("" : "+v"(rax), "+v"(ray) : "v"(hbp), "v"(hbm)); \
        const float reax = (EAXI), reay = (EAYI); \
        const float peax = (EAXP), peay = (EAYP); \
        float rmax = -1e38f; \
        BR2(ebx0,eby0, ebx7,eby7, bx0,by0, mbmin0) \
        BR2(ebx1,eby1, ebx0,eby0, bx1,by1, mbmin1) \
        BR2(ebx2,eby2, ebx1,eby1, bx2,by2, mbmin2) \
        BR2(ebx3,eby3, ebx2,eby2, bx3,by3, mbmin3) \
        BR2(ebx4,eby4, ebx3,eby3, bx4,by4, mbmin4) \
        BR2(ebx5,eby5, ebx4,eby4, bx5,by5, mbmin5) \
        BR2(ebx6,eby6, ebx5,eby5, bx6,by6, mbmin6) \
        BR2(ebx7,eby7, ebx6,eby6, bx7,by7, mbmin7) \
        eSa += (rmax <= 0.f) ? (CAI) : 0.f; }

    BRROW(ax0,ay0, eax0,eay0, eax7,eay7, ca0)
    BRROW(ax1,ay1, eax1,eay1, eax0,eay0, ca1)
    BRROW(ax2,ay2, eax2,eay2, eax1,eay1, ca2)
    BRROW(ax3,ay3, eax3,eay3, eax2,eay2, ca3)
    BRROW(ax4,ay4, eax4,eay4, eax3,eay3, ca4)
    BRROW(ax5,ay5, eax5,eay5, eax4,eay4, ca5)
    BRROW(ax6,ay6, eax6,eay6, eax5,eay5, ca6)
    BRROW(ax7,ay7, eax7,eay7, eax6,eay6, ca7)

    float eSb = (((mbmin0 >= 0.f ? cb0 : 0.f) + (mbmin1 >= 0.f ? cb1 : 0.f))
              +  ((mbmin2 >= 0.f ? cb2 : 0.f) + (mbmin3 >= 0.f ? cb3 : 0.f)))
              + (((mbmin4 >= 0.f ? cb4 : 0.f) + (mbmin5 >= 0.f ? cb5 : 0.f))
              +  ((mbmin6 >= 0.f ? cb6 : 0.f) + (mbmin7 >= 0.f ? cb7 : 0.f)));
    float ch = 0.5f * ((eSa + eSb) + (hbp - hbm));

    float val = iou - __fdividef(ch - uni, ch);
    float v = live ? val : 0.f;

    // ---- epilogue: shuffle -> LDS(16B) -> ONE plain store. Zero waits. ----
    #pragma unroll
    for (int off = 32; off > 0; off >>= 1) v += __shfl_down(v, off);
    __shared__ float wsum[4];
    int lane = t & 63, wid = t >> 6;
    if (lane == 0) wsum[wid] = v;
    __syncthreads();
    if (t == 0) {
        partial[blockIdx.x] = (double)wsum[0] + (double)wsum[1]
                            + (double)wsum[2] + (double)wsum[3];
    }
}

__global__ __launch_bounds__(256) void ciou_finalize(
    const double* __restrict__ partial, float* __restrict__ out,
    int nparts, int nbatch)
{
    double v = 0.0;
    for (int j = threadIdx.x; j < nparts; j += 256) v += partial[j];
    #pragma unroll
    for (int off = 32; off > 0; off >>= 1) v += __shfl_down(v, off);
    __shared__ double s[4];
    int lane = threadIdx.x & 63, wid = threadIdx.x >> 6;
    if (lane == 0) s[wid] = v;
    __syncthreads();
    if (threadIdx.x == 0)
        out[0] = (float)((s[0] + s[1] + s[2] + s[3]) / (double)nbatch);
}

extern "C" void kernel_launch(void* const* d_in, const int* in_sizes, int n_in,
                              void* d_out, int out_size, void* d_ws, size_t ws_size,
                              hipStream_t stream) {
    const float* a = (const float*)d_in[0];
    const float* b = (const float*)d_in[1];
    float* out = (float*)d_out;
    int nbatch = in_sizes[0] / 16;
    int nblocks = (nbatch + TPB - 1) / TPB;   // 262144 -> 1024, exact
    int tail = (nblocks * TPB != nbatch) ? 1 : 0;
    double* partial = (double*)d_ws;   // fully overwritten each call; no memset
    ciou_main<<<nblocks, TPB, 0, stream>>>(a, b, partial, nbatch, tail);
    ciou_finalize<<<1, 256, 0, stream>>>(partial, out, nblocks, nbatch);
}